// Round 1
// baseline (281.950 us; speedup 1.0000x reference)
//
#include <hip/hip_runtime.h>

// Problem constants
#define QN    2048
#define SS    8
#define DD    2048
#define SP    100
#define NCLS  20
#define MROWS (QN*SS)       // 16384 GEMM M
#define NREAL (SP*SS)       // 800 real support rows
#define NPAD  1024          // padded N: 4 full 256-tiles, uniform grid
#define KK    DD
#define BK    64
#define NTK   (KK/BK)       // 32 K-tiles

typedef __bf16 bf16x8 __attribute__((ext_vector_type(8)));
typedef float  f32x4  __attribute__((ext_vector_type(4)));

__device__ __forceinline__ unsigned short f2bf(float f) {
    unsigned int u = __float_as_uint(f);
    u += 0x7fffu + ((u >> 16) & 1u);   // round-to-nearest-even
    return (unsigned short)(u >> 16);
}

// ---------------- Kernel 1: fp32 -> bf16 + row L2 norms + out zeroing + B pad zeroing ----
// One WAVE per row. 4 rows per 256-thread block.
__global__ void cvt_kernel(const float* __restrict__ tf, const float* __restrict__ sf,
                           unsigned short* __restrict__ Abf, unsigned short* __restrict__ Bbf,
                           float* __restrict__ nA, float* __restrict__ nB,
                           float* __restrict__ out)
{
    // zero the logits output (gemm accumulates atomically): 160*256 = 40960 elems
    if (blockIdx.x < 160) out[blockIdx.x * 256 + threadIdx.x] = 0.f;

    const int wv   = threadIdx.x >> 6;
    const int lane = threadIdx.x & 63;
    const int row  = blockIdx.x * 4 + wv;       // 0 .. 17407

    const float* src;
    unsigned short* dst;
    float* nrm; int r;
    if (row < MROWS) { src = tf + (size_t)row * DD; dst = Abf + (size_t)row * DD; nrm = nA; r = row; }
    else {
        r = row - MROWS;                        // 0..1023
        if (r >= NREAL) {                       // pad rows: zero-fill so GEMM acc is exactly 0
            unsigned short* d2 = Bbf + (size_t)r * DD;
            ushort4 z = make_ushort4(0, 0, 0, 0);
#pragma unroll
            for (int j = 0; j < 8; ++j) *(ushort4*)(d2 + j * 256 + lane * 4) = z;
            if (lane == 0) nB[r] = 0.f;
            return;
        }
        src = sf + (size_t)r * DD; dst = Bbf + (size_t)r * DD; nrm = nB;
    }

    float s = 0.f;
#pragma unroll
    for (int j = 0; j < 8; j++) {
        float4 v = *(const float4*)(src + j * 256 + lane * 4);
        s += v.x*v.x + v.y*v.y + v.z*v.z + v.w*v.w;
        ushort4 pk = make_ushort4(f2bf(v.x), f2bf(v.y), f2bf(v.z), f2bf(v.w));
        *(ushort4*)(dst + j * 256 + lane * 4) = pk;
    }
#pragma unroll
    for (int o = 32; o; o >>= 1) s += __shfl_down(s, o);
    if (lane == 0) nrm[r] = sqrtf(s);
}

// ---------------- softmin helpers ----------------
__device__ __forceinline__ float softmin2(float a, float b) {
    float mn = fminf(a, b), mx = fmaxf(a, b);
    return mn - 0.1f * __logf(1.0f + __expf((mn - mx) * 10.0f));
}
__device__ __forceinline__ float softmin3(float a, float b, float c) {
    float mn = fminf(fminf(a, b), c);
    float sum = __expf((mn - a) * 10.0f) + __expf((mn - b) * 10.0f) + __expf((mn - c) * 10.0f);
    return mn - 0.1f * __logf(sum);
}

__device__ __forceinline__ void gld16(const void* g, void* l) {
    __builtin_amdgcn_global_load_lds(
        (const __attribute__((address_space(1))) unsigned int*)g,
        (__attribute__((address_space(3))) unsigned int*)l, 16, 0, 0);
}

// bf16 cell (a,b) of lane's 8x8 tile held in 8 uint4 registers -> fp32
__device__ __forceinline__ float cellf(const uint4* raw, int a, int b) {
    const unsigned* p = (const unsigned*)raw;
    unsigned wv = p[a * 4 + (b >> 1)];
    return __uint_as_float((b & 1) ? (wv & 0xffff0000u) : (wv << 16));
}

// OTAM DP over the lane's 8x8 tile (dir selects transpose), returns final cost
__device__ __forceinline__ float otam_dp(const uint4* raw, int dir) {
    float prev[10], cur[10];
    prev[0] = 0.f;
#pragma unroll
    for (int m = 1; m <= 8; m++) {
        float v0 = cellf(raw, 0, m - 1), v1 = cellf(raw, m - 1, 0);
        prev[m] = prev[m - 1] + (dir ? v1 : v0);
    }
    prev[9] = prev[8];
#pragma unroll
    for (int l = 1; l < 8; l++) {
        float d[8];
#pragma unroll
        for (int j = 0; j < 8; j++) {
            float v0 = cellf(raw, l, j), v1 = cellf(raw, j, l);
            d[j] = dir ? v1 : v0;
        }
        cur[1] = d[0] + softmin3(prev[0], prev[1], 0.0f);
#pragma unroll
        for (int m = 2; m <= 8; m++)
            cur[m] = d[m - 1] + softmin2(prev[m - 1], cur[m - 1]);
        cur[9] = softmin3(prev[8], prev[9], cur[8]);   // pad column: d=0
#pragma unroll
        for (int m = 1; m < 10; m++) prev[m] = cur[m];
    }
    return prev[9];
}

// ======================= Kernel 2: 256x256 8-phase fused GEMM + DP =======================
// 8 waves (2M x 4N), BK=64, double-buffered 128 KiB LDS, XOR-swizzled A/B tiles,
// counted vmcnt (6 mid-tile, 2 at tile boundary), setprio around MFMA clusters.
//
// LDS layout per buffer d (d*65536 bytes):
//   A: rows 0..255 at row*128 B, 8 swizzled 16B k-slots: phys slot = kslot ^ (row&7)
//   B: +32768, same layout (rows = N cols of the tile)
// Staging writes are linear (global_load_lds); the swizzle is baked into the per-lane
// GLOBAL source k-offset (rule #21: both-sides-or-neither).
__global__ __launch_bounds__(512, 2) void gemm_kernel(
    const unsigned short* __restrict__ A,   // [MROWS][K] bf16 bits
    const unsigned short* __restrict__ B,   // [NPAD][K]  bf16 bits (rows >=800 zeroed)
    const float* __restrict__ nA, const float* __restrict__ nB,
    const int* __restrict__ labels,
    float* __restrict__ out)                // [QN][NCLS], zeroed by cvt
{
    extern __shared__ __align__(16) char lds8[];   // 131072 B dynamic

    const int mt   = blockIdx.x;            // 0..63
    const int nt   = blockIdx.y;            // 0..3
    const int tid  = threadIdx.x;
    const int lane = tid & 63;
    const int w    = tid >> 6;              // 0..7
    const int wm   = w >> 2, wn = w & 3;    // 2 x 4 wave grid
    const int col  = lane & 15, kg = lane >> 4;
    const int mbase = mt * 256, nbase = nt * 256;

    // ---- staging addressing (pre-swizzled global source, linear LDS dest) ----
    // thread covers row (base + w*8 + lane>>3), phys k-slot (lane&7); logical kslot = phys ^ (row&7)
    const int ks8 = ((lane & 7) ^ (lane >> 3)) << 3;                 // shorts
    const unsigned short* sA = A + (size_t)(mbase + w * 8 + (lane >> 3)) * KK + ks8;
    const unsigned short* sB = B + (size_t)(nbase + w * 8 + (lane >> 3)) * KK + ks8;
    const int stoff = w * 1024 + lane * 16;                          // bytes, linear per wave

    // ---- ds_read addressing (swizzled) ----
    const int sb16 = ((kg ^ (col & 7)) << 4);                        // phys slot*16 for kk=0
    const int arow = (wm * 128 + col) * 128;                         // A frag row base (bytes)
    const int brow = 32768 + (wn * 64 + col) * 128;                  // B frag row base (bytes)

    f32x4 acc[8][4] = {};

    // ---- prologue: stage tile 0 into buffer 0 (8 loads), drain once ----
    gld16(sB,                       lds8 + 32768 + stoff);           // B rows   0- 63
    gld16(sB + (size_t) 64 * KK,    lds8 + 32768 +  8192 + stoff);   // B rows  64-127
    gld16(sB + (size_t)128 * KK,    lds8 + 32768 + 16384 + stoff);   // B rows 128-191
    gld16(sB + (size_t)192 * KK,    lds8 + 32768 + 24576 + stoff);   // B rows 192-255
    gld16(sA,                       lds8 + stoff);                   // A rows   0- 63 (lo)
    gld16(sA + (size_t)128 * KK,    lds8 + 16384 + stoff);           // A rows 128-191 (lo)
    gld16(sA + (size_t) 64 * KK,    lds8 +  8192 + stoff);           // A rows  64-127 (hi)
    gld16(sA + (size_t)192 * KK,    lds8 + 24576 + stoff);           // A rows 192-255 (hi)
    asm volatile("s_waitcnt vmcnt(0)" ::: "memory");
    __builtin_amdgcn_s_barrier();

    for (int t = 0; t < NTK; ++t) {
        const int cb = (t & 1) << 16;       // current buffer byte base
        const int nb = cb ^ 65536;          // next buffer
        const bool st = (t + 1 < NTK);
        const int t1 = (t + 1) * BK;        // shorts
        bf16x8 af[4], bf0[4], bf1[4];

        // ================= phase 0: mi0-3 @ kk0 ; stage B(t+1) [4 loads] =================
#pragma unroll
        for (int i = 0; i < 4; ++i)
            af[i]  = *(const bf16x8*)(lds8 + cb + arow + i * 2048 + sb16);
#pragma unroll
        for (int n = 0; n < 4; ++n)
            bf0[n] = *(const bf16x8*)(lds8 + cb + brow + n * 2048 + sb16);
        if (st) {
            gld16(sB + t1,                    lds8 + nb + 32768 + stoff);
            gld16(sB + (size_t) 64 * KK + t1, lds8 + nb + 32768 +  8192 + stoff);
            gld16(sB + (size_t)128 * KK + t1, lds8 + nb + 32768 + 16384 + stoff);
            gld16(sB + (size_t)192 * KK + t1, lds8 + nb + 32768 + 24576 + stoff);
        }
        __builtin_amdgcn_s_barrier();
        asm volatile("s_waitcnt lgkmcnt(0)" ::: "memory");
        __builtin_amdgcn_sched_barrier(0);
        __builtin_amdgcn_s_setprio(1);
#pragma unroll
        for (int mi = 0; mi < 4; ++mi)
#pragma unroll
            for (int n = 0; n < 4; ++n)
                acc[mi][n] = __builtin_amdgcn_mfma_f32_16x16x32_bf16(af[mi], bf0[n], acc[mi][n], 0, 0, 0);
        __builtin_amdgcn_s_setprio(0);
        __builtin_amdgcn_sched_barrier(0);
        __builtin_amdgcn_s_barrier();

        // ================= phase 1: mi0-3 @ kk1 ; stage A-lo(t+1) [2] ; vmcnt(6) =========
        // vmcnt(6) leaves {A-lo(t+1), B(t+1)} in flight => A-hi(t) guaranteed landed.
#pragma unroll
        for (int i = 0; i < 4; ++i)
            af[i]  = *(const bf16x8*)(lds8 + cb + arow + i * 2048 + (sb16 ^ 64));
#pragma unroll
        for (int n = 0; n < 4; ++n)
            bf1[n] = *(const bf16x8*)(lds8 + cb + brow + n * 2048 + (sb16 ^ 64));
        if (st) {
            gld16(sA + t1,                    lds8 + nb + stoff);
            gld16(sA + (size_t)128 * KK + t1, lds8 + nb + 16384 + stoff);
        }
        asm volatile("s_waitcnt vmcnt(6)" ::: "memory");
        __builtin_amdgcn_s_barrier();
        asm volatile("s_waitcnt lgkmcnt(0)" ::: "memory");
        __builtin_amdgcn_sched_barrier(0);
        __builtin_amdgcn_s_setprio(1);
#pragma unroll
        for (int mi = 0; mi < 4; ++mi)
#pragma unroll
            for (int n = 0; n < 4; ++n)
                acc[mi][n] = __builtin_amdgcn_mfma_f32_16x16x32_bf16(af[mi], bf1[n], acc[mi][n], 0, 0, 0);
        __builtin_amdgcn_s_setprio(0);
        __builtin_amdgcn_sched_barrier(0);
        __builtin_amdgcn_s_barrier();

        // ================= phase 2: mi4-7 @ kk0 (reuse bf0) ; stage A-hi(t+1) [2] ========
#pragma unroll
        for (int i = 0; i < 4; ++i)
            af[i] = *(const bf16x8*)(lds8 + cb + arow + 8192 + i * 2048 + sb16);
        if (st) {
            gld16(sA + (size_t) 64 * KK + t1, lds8 + nb +  8192 + stoff);
            gld16(sA + (size_t)192 * KK + t1, lds8 + nb + 24576 + stoff);
        }
        __builtin_amdgcn_s_barrier();
        asm volatile("s_waitcnt lgkmcnt(0)" ::: "memory");
        __builtin_amdgcn_sched_barrier(0);
        __builtin_amdgcn_s_setprio(1);
#pragma unroll
        for (int mi = 0; mi < 4; ++mi)
#pragma unroll
            for (int n = 0; n < 4; ++n)
                acc[4 + mi][n] = __builtin_amdgcn_mfma_f32_16x16x32_bf16(af[mi], bf0[n], acc[4 + mi][n], 0, 0, 0);
        __builtin_amdgcn_s_setprio(0);
        __builtin_amdgcn_sched_barrier(0);
        __builtin_amdgcn_s_barrier();

        // ================= phase 3: mi4-7 @ kk1 (reuse bf1) ; vmcnt(2) ===================
        // vmcnt(2) leaves {A-hi(t+1)} in flight => B(t+1)+A-lo(t+1) guaranteed for next phase 0.
#pragma unroll
        for (int i = 0; i < 4; ++i)
            af[i] = *(const bf16x8*)(lds8 + cb + arow + 8192 + i * 2048 + (sb16 ^ 64));
        asm volatile("s_waitcnt vmcnt(2)" ::: "memory");
        __builtin_amdgcn_s_barrier();
        asm volatile("s_waitcnt lgkmcnt(0)" ::: "memory");
        __builtin_amdgcn_sched_barrier(0);
        __builtin_amdgcn_s_setprio(1);
#pragma unroll
        for (int mi = 0; mi < 4; ++mi)
#pragma unroll
            for (int n = 0; n < 4; ++n)
                acc[4 + mi][n] = __builtin_amdgcn_mfma_f32_16x16x32_bf16(af[mi], bf1[n], acc[4 + mi][n], 0, 0, 0);
        __builtin_amdgcn_s_setprio(0);
        __builtin_amdgcn_sched_barrier(0);
        __builtin_amdgcn_s_barrier();
    }

    // ======================= fused epilogue: cos-dist -> OTAM DP -> class mean ===========
    __syncthreads();
    unsigned short* eb = (unsigned short*)lds8 + w * 2304;   // 32 rows x 64 cols, stride 72
    const int pr  = lane & 31;
    const int qv2 = pr >> 3, sv = pr & 7;
    const int dir = lane >> 5;

#pragma unroll
    for (int p = 0; p < 4; ++p) {
        if (p) __syncthreads();
#pragma unroll
        for (int mi2 = 0; mi2 < 2; ++mi2) {
            const int mi = p * 2 + mi2;
            float nx[4];
#pragma unroll
            for (int r = 0; r < 4; ++r) nx[r] = nA[mbase + wm * 128 + mi * 16 + kg * 4 + r];
#pragma unroll
            for (int ni = 0; ni < 4; ++ni) {
                const float ny = nB[nbase + wn * 64 + ni * 16 + col];
#pragma unroll
                for (int r = 0; r < 4; ++r) {
                    float d = 1.0f - acc[mi][ni][r] * __builtin_amdgcn_rcpf(nx[r] * ny + 0.01f);
                    eb[(mi2 * 16 + kg * 4 + r) * 72 + ni * 16 + col] = f2bf(d);
                }
            }
        }
        __syncthreads();

        uint4 raw[8];
        const unsigned short* tb = eb + (qv2 * 8) * 72 + sv * 8;
#pragma unroll
        for (int l = 0; l < 8; ++l) raw[l] = *(const uint4*)(tb + l * 72);

        float res = otam_dp(raw, dir);
        res += __shfl_down(res, 32);
        if (dir == 0) {
            const int sg = nt * 32 + wn * 8 + sv;
            if (sg < SP) {
                const int qg = mt * 32 + wm * 16 + p * 4 + qv2;
                atomicAdd(out + (size_t)qg * NCLS + labels[sg], -res * 0.2f);
            }
        }
    }
}

// ---------------- launch ----------------
extern "C" void kernel_launch(void* const* d_in, const int* in_sizes, int n_in,
                              void* d_out, int out_size, void* d_ws, size_t ws_size,
                              hipStream_t stream)
{
    const float* tf     = (const float*)d_in[0];   // [2048,8,2048] f32
    const float* sf     = (const float*)d_in[1];   // [100,8,2048]  f32
    const int*   labels = (const int*)d_in[2];     // [100] i32
    float* out = (float*)d_out;                    // [1,2048,20] f32

    char* ws = (char*)d_ws;
    const size_t szA    = (size_t)MROWS * KK * 2;      // 67108864
    const size_t szB    = (size_t)NPAD  * KK * 2;      // 4194304
    const size_t szNA   = (size_t)MROWS * 4;           // 65536
    unsigned short* Abf = (unsigned short*)ws;
    unsigned short* Bbf = (unsigned short*)(ws + szA);
    float* nA   = (float*)(ws + szA + szB);
    float* nB   = (float*)(ws + szA + szB + szNA);

    static int inited = 0;
    if (!inited) {
        (void)hipFuncSetAttribute((const void*)gemm_kernel,
                                  hipFuncAttributeMaxDynamicSharedMemorySize, 131072);
        inited = 1;
    }

    cvt_kernel<<<(MROWS + NPAD) / 4, 256, 0, stream>>>(tf, sf, Abf, Bbf, nA, nB, out);
    gemm_kernel<<<dim3(MROWS / 256, NPAD / 256), 512, 131072, stream>>>(Abf, Bbf, nA, nB, labels, out);
}